// Round 4
// baseline (99.147 us; speedup 1.0000x reference)
//
#include <hip/hip_runtime.h>
#include <hip/hip_bf16.h>

#define B_ 8
#define T_ 12
#define N_ 2048
#define C_ 64
#define BM 128
#define BK 64

typedef __attribute__((ext_vector_type(4))) float f32x4;
typedef __attribute__((ext_vector_type(4))) __bf16 bf16x4;
typedef __attribute__((ext_vector_type(8))) __bf16 bf16x8;

#define GAS __attribute__((address_space(1)))
#define LAS __attribute__((address_space(3)))

static __device__ __forceinline__ void gld_lds16(const void* g, void* l) {
    __builtin_amdgcn_global_load_lds((const GAS void*)g, (LAS void*)l, 16, 0, 0);
}

// ws layout (bytes)
#define WS_CBUF 0
#define WS_WTB  1024
#define WS_ADJB 32768
#define WS_XT   (32768 + 8388608)
#define WS_NEED ((size_t)(WS_XT) + 25165824)

// ---------------- lambda MLP (fallback path) ----------------
__global__ void lam_kernel(const float* __restrict__ st, const float* __restrict__ W1,
                           const float* __restrict__ b1, const float* __restrict__ W2,
                           const float* __restrict__ b2, float* __restrict__ cbuf) {
    const int t = threadIdx.x >> 5;
    const int h = threadIdx.x & 31;
    if (t >= T_) return;
    float acc = b1[h];
    #pragma unroll 8
    for (int e = 0; e < 64; ++e) acc += st[t * 64 + e] * W1[e * 32 + h];
    float hv = fmaxf(acc, 0.f) * W2[h];
    #pragma unroll
    for (int off = 16; off; off >>= 1) hv += __shfl_down(hv, off, 32);
    if (h == 0) {
        float lam = 1.f + fmaxf(hv + b2[0], 0.f);
        cbuf[t]      = 2.f - 2.f / lam;
        cbuf[T_ + t] = 2.f / lam;
    }
}

// ---------------- lambda MLP + Wcat->bf16 (fast path) ----------------
__global__ void lamw_kernel(const float* __restrict__ st, const float* __restrict__ W1,
                            const float* __restrict__ b1, const float* __restrict__ W2,
                            const float* __restrict__ b2, const float* __restrict__ weights,
                            float* __restrict__ cbuf, __bf16* __restrict__ WtB) {
    const int t = threadIdx.x >> 5;
    const int h = threadIdx.x & 31;
    if (t < T_) {
        float acc = b1[h];
        #pragma unroll 8
        for (int e = 0; e < 64; ++e) acc += st[t * 64 + e] * W1[e * 32 + h];
        float hv = fmaxf(acc, 0.f) * W2[h];
        #pragma unroll
        for (int off = 16; off; off >>= 1) hv += __shfl_down(hv, off, 32);
        if (h == 0) {
            float lam = 1.f + fmaxf(hv + b2[0], 0.f);
            cbuf[t]      = 2.f - 2.f / lam;
            cbuf[T_ + t] = 2.f / lam;
        }
    }
    // WtB[o][k]: k<64 -> W1supp = weights[1][k][o] ; k>=64 -> W0 = weights[0][k-64][o]
    for (int e = threadIdx.x; e < 64 * 128; e += 512) {
        int o = e >> 7, k = e & 127;
        float v = (k < 64) ? weights[4096 + k * 64 + o] : weights[(k - 64) * 64 + o];
        WtB[o * 128 + k] = (__bf16)v;
    }
}

// ---------------- fused fp32->bf16 converts: x (transposed) + adj ----------------
// blocks [0, 3072): xT ;  blocks [3072, 5120): adj
__global__ void cvt_fused(const float* __restrict__ x, __bf16* __restrict__ xT,
                          const float* __restrict__ adj, __bf16* __restrict__ adjb) {
    const int bid = blockIdx.x;
    const int tid = threadIdx.x;
    if (bid >= 3072) {
        const size_t i = ((size_t)(bid - 3072) * 256 + tid) * 8;
        const float4 f0 = *(const float4*)&adj[i];
        const float4 f1 = *(const float4*)&adj[i + 4];
        bf16x8 h = { (__bf16)f0.x, (__bf16)f0.y, (__bf16)f0.z, (__bf16)f0.w,
                     (__bf16)f1.x, (__bf16)f1.y, (__bf16)f1.z, (__bf16)f1.w };
        *(bf16x8*)&adjb[i] = h;
        return;
    }
    __shared__ __align__(16) __bf16 t[64][72];
    const int bt = bid >> 5, n0 = (bid & 31) * 64;
    {
        const int r = tid >> 2, c0 = (tid & 3) * 16;
        const float* src = x + ((size_t)bt * N_ + n0 + r) * C_ + c0;
        #pragma unroll
        for (int i = 0; i < 4; ++i) {
            float4 f = *(const float4*)(src + 4 * i);
            t[c0 + 4 * i + 0][r] = (__bf16)f.x;
            t[c0 + 4 * i + 1][r] = (__bf16)f.y;
            t[c0 + 4 * i + 2][r] = (__bf16)f.z;
            t[c0 + 4 * i + 3][r] = (__bf16)f.w;
        }
    }
    __syncthreads();
    {
        const int c = tid >> 2, nf = (tid & 3) * 16;
        __bf16* dst = xT + ((size_t)bt * C_ + c) * N_ + n0 + nf;
        *(bf16x8*)(dst)     = *(const bf16x8*)&t[c][nf];
        *(bf16x8*)(dst + 8) = *(const bf16x8*)&t[c][nf + 8];
    }
}

// ---------------- fast main kernel (2-phase double-buffered) ----------------
// LDS 64 KB: buf0 = { A [0,16K), B [16K,32K) }, buf1 = { A [32K,48K), B [48K,64K) }.
// Epilogue E [0,32K) reuses buf0. Wt fragments read from global (L2-hot).
__global__ __launch_bounds__(256, 2) void dgcn_main2(
    const __bf16* __restrict__ adjb, const __bf16* __restrict__ xT,
    const float* __restrict__ x, const __bf16* __restrict__ WtB,
    const float* __restrict__ bias, const float* __restrict__ cbuf,
    float* __restrict__ out)
{
    __shared__ __align__(16) __bf16 smem[32768];   // 65536 B
    char* sb = (char*)smem;

    const int m0  = blockIdx.x * BM;
    const int btg = blockIdx.y;                    // 0..47 (2 bt each)
    const int tid = threadIdx.x;
    const int l   = tid & 63, w = tid >> 6;
    const int wr  = w >> 1, wc = w & 1;
    const int lr  = l & 15, lk = l >> 4;           // lk in 0..3

    // --- per-lane inverse-swizzled global sources for global_load_lds ---
    const __bf16* srcA[4];
    const __bf16* srcB[4];
    #pragma unroll
    for (int i = 0; i < 4; ++i) {
        int s = (w * 4 + i) * 64 + l;              // 0..1023
        int r = s >> 3, j = s & 7;                 // As rows are 128 B = 8 slots
        srcA[i] = adjb + (size_t)(m0 + r) * N_ + 8 * (j ^ (r & 7));
        int bb = s >> 9, c = (s >> 3) & 63;
        srcB[i] = xT + ((size_t)(btg * 2 + bb) * C_ + c) * N_ + 8 * (j ^ (c & 7));
    }

    f32x4 acc[4][4] = {};

    // prologue: stage kt=0 into buf0
    #pragma unroll
    for (int i = 0; i < 4; ++i) {
        gld_lds16(srcA[i], sb + (w * 4 + i) * 1024);
        gld_lds16(srcB[i], sb + 16384 + (w * 4 + i) * 1024);
    }

    int sel = 0;
    for (int kt = 0; kt < N_ / BK; ++kt) {
        __syncthreads();   // compiler drains vmcnt(0): buf[sel] ready; prev reads of buf[sel^1] done
        if (kt < N_ / BK - 1) {
            const int wo = (sel ^ 1) * 32768;
            #pragma unroll
            for (int i = 0; i < 4; ++i) {
                srcA[i] += BK;
                srcB[i] += BK;
                gld_lds16(srcA[i], sb + wo + (w * 4 + i) * 1024);
                gld_lds16(srcB[i], sb + wo + 16384 + (w * 4 + i) * 1024);
            }
        }
        const char* base = sb + sel * 32768;
        #pragma unroll
        for (int ks = 0; ks < 2; ++ks) {
            const int kb = ks * 64 + lk * 16;
            bf16x8 a[4];
            #pragma unroll
            for (int mi = 0; mi < 4; ++mi) {
                int rr = wr * 64 + mi * 16 + lr;
                a[mi] = *(const bf16x8*)(base + rr * 128 + (kb ^ ((rr & 7) << 4)));
            }
            #pragma unroll
            for (int nj = 0; nj < 4; ++nj) {
                int cc = nj * 16 + lr;
                bf16x8 b = *(const bf16x8*)(base + 16384 + wc * 8192 + cc * 128 + (kb ^ ((cc & 7) << 4)));
                #pragma unroll
                for (int mi = 0; mi < 4; ++mi)
                    acc[mi][nj] = __builtin_amdgcn_mfma_f32_16x16x32_bf16(a[mi], b, acc[mi][nj], 0, 0, 0);
            }
        }
        sel ^= 1;
    }

    // ---------------- epilogue: per bt, E = [c2*Y | c1*x], out = E @ Wt + bias ----------------
    #pragma unroll
    for (int bb = 0; bb < 2; ++bb) {
        const int btA = btg * 2 + bb;
        const int tloc = btA % T_;
        const float c1 = cbuf[tloc];
        const float c2 = cbuf[T_ + tloc];
        __syncthreads();                           // E region free
        if (wc == bb) {                            // Y part (cols 0..63)
            #pragma unroll
            for (int mi = 0; mi < 4; ++mi)
                #pragma unroll
                for (int nj = 0; nj < 4; ++nj)
                    #pragma unroll
                    for (int q = 0; q < 4; ++q) {
                        int row = wr * 64 + mi * 16 + lk * 4 + q;
                        int colb = (nj * 16 + lr) * 2;
                        *(__bf16*)(sb + row * 256 + (colb ^ ((row & 7) << 4))) =
                            (__bf16)(c2 * acc[mi][nj][q]);
                    }
        }
        {                                          // identity part (cols 64..127)
            int row = w * 32 + (l >> 1);
            int c0 = (l & 1) * 32;
            const float* xs = x + ((size_t)btA * N_ + m0 + row) * C_ + c0;
            #pragma unroll
            for (int i = 0; i < 4; ++i) {
                float4 f0 = *(const float4*)(xs + 8 * i);
                float4 f1 = *(const float4*)(xs + 8 * i + 4);
                bf16x8 h = { (__bf16)(c1 * f0.x), (__bf16)(c1 * f0.y),
                             (__bf16)(c1 * f0.z), (__bf16)(c1 * f0.w),
                             (__bf16)(c1 * f1.x), (__bf16)(c1 * f1.y),
                             (__bf16)(c1 * f1.z), (__bf16)(c1 * f1.w) };
                int colb = 128 + c0 * 2 + 16 * i;
                *(bf16x8*)(sb + row * 256 + (colb ^ ((row & 7) << 4))) = h;
            }
        }
        __syncthreads();
        f32x4 oacc[2][4] = {};
        #pragma unroll
        for (int ks = 0; ks < 4; ++ks) {
            const int kb = ks * 64 + lk * 16;
            bf16x8 ea[2];
            #pragma unroll
            for (int mi2 = 0; mi2 < 2; ++mi2) {
                int row = w * 32 + mi2 * 16 + lr;
                ea[mi2] = *(const bf16x8*)(sb + row * 256 + (kb ^ ((row & 7) << 4)));
            }
            #pragma unroll
            for (int nj = 0; nj < 4; ++nj) {
                int o = nj * 16 + lr;
                bf16x8 bw = *(const bf16x8*)(WtB + o * 128 + ks * 32 + lk * 8);  // linear, L2-hot
                oacc[0][nj] = __builtin_amdgcn_mfma_f32_16x16x32_bf16(ea[0], bw, oacc[0][nj], 0, 0, 0);
                oacc[1][nj] = __builtin_amdgcn_mfma_f32_16x16x32_bf16(ea[1], bw, oacc[1][nj], 0, 0, 0);
            }
        }
        float* ob = out + (size_t)btA * N_ * C_;
        #pragma unroll
        for (int nj = 0; nj < 4; ++nj) {
            const float bv = bias[nj * 16 + lr];
            #pragma unroll
            for (int mi2 = 0; mi2 < 2; ++mi2)
                #pragma unroll
                for (int q = 0; q < 4; ++q) {
                    int row = w * 32 + mi2 * 16 + lk * 4 + q;
                    ob[(size_t)(m0 + row) * C_ + nj * 16 + lr] = oacc[mi2][nj][q] + bv;
                }
        }
    }
}

// ---------------- fallback (round-1 verified) ----------------
#define LDM 72
#define LDE 136
__global__ __launch_bounds__(256, 3) void dgcn_fb(
    const float* __restrict__ x, const float* __restrict__ adj,
    const float* __restrict__ weights, const float* __restrict__ bias,
    const float* __restrict__ cbuf, float* __restrict__ out)
{
    __shared__ __align__(16) __bf16 smem[BM * LDE];
    __shared__ __align__(16) __bf16 Wt[64 * LDE];
    __bf16* As = smem;
    __bf16* Bs = smem + BM * LDM;
    __bf16* E  = smem;

    const int mtile = blockIdx.x;
    const int bt    = blockIdx.y;
    const int tloc  = bt % T_;
    const int m0    = mtile * BM;
    const int tid   = threadIdx.x;
    const int lane  = tid & 63;
    const int w     = tid >> 6;

    const float c1 = cbuf[tloc];
    const float c2 = cbuf[T_ + tloc];
    const float* xbt = x + (size_t)bt * N_ * C_;

    for (int e = tid; e < 2 * 64 * 64; e += 256) {
        int kk = e >> 6, o = e & 63;
        float v = (kk < 64) ? weights[4096 + kk * 64 + o] : weights[(kk - 64) * 64 + o];
        Wt[o * LDE + kk] = (__bf16)v;
    }

    f32x4 acc[2][4] = {};
    const int c4 = tid & 15;
    const int rg = tid >> 4;
    const int lr = lane & 15;
    const int lk = lane >> 4;

    for (int kt = 0; kt < N_ / BK; ++kt) {
        const int k0 = kt * BK;
        __syncthreads();
        #pragma unroll
        for (int j = 0; j < 8; ++j) {
            const int r = rg + 16 * j;
            const float4 f = *(const float4*)&adj[(size_t)(m0 + r) * N_ + k0 + 4 * c4];
            bf16x4 h = { (__bf16)f.x, (__bf16)f.y, (__bf16)f.z, (__bf16)f.w };
            *(bf16x4*)&As[r * LDM + 4 * c4] = h;
        }
        #pragma unroll
        for (int j = 0; j < 4; ++j) {
            const int k  = (tid & 15) + 16 * j;
            const int c0 = 4 * (tid >> 4);
            const float4 f = *(const float4*)&xbt[(size_t)(k0 + k) * C_ + c0];
            Bs[(c0 + 0) * LDM + k] = (__bf16)f.x;
            Bs[(c0 + 1) * LDM + k] = (__bf16)f.y;
            Bs[(c0 + 2) * LDM + k] = (__bf16)f.z;
            Bs[(c0 + 3) * LDM + k] = (__bf16)f.w;
        }
        __syncthreads();
        #pragma unroll
        for (int ks = 0; ks < 2; ++ks) {
            bf16x8 a0 = *(const bf16x8*)&As[(w * 32 +  0 + lr) * LDM + ks * 32 + lk * 8];
            bf16x8 a1 = *(const bf16x8*)&As[(w * 32 + 16 + lr) * LDM + ks * 32 + lk * 8];
            #pragma unroll
            for (int nj = 0; nj < 4; ++nj) {
                bf16x8 b = *(const bf16x8*)&Bs[(nj * 16 + lr) * LDM + ks * 32 + lk * 8];
                acc[0][nj] = __builtin_amdgcn_mfma_f32_16x16x32_bf16(a0, b, acc[0][nj], 0, 0, 0);
                acc[1][nj] = __builtin_amdgcn_mfma_f32_16x16x32_bf16(a1, b, acc[1][nj], 0, 0, 0);
            }
        }
    }
    __syncthreads();

    #pragma unroll
    for (int j = 0; j < 8; ++j) {
        const int r = rg + 16 * j;
        const float4 f = *(const float4*)&xbt[(size_t)(m0 + r) * C_ + 4 * c4];
        bf16x4 h = { (__bf16)(c1 * f.x), (__bf16)(c1 * f.y), (__bf16)(c1 * f.z), (__bf16)(c1 * f.w) };
        *(bf16x4*)&E[r * LDE + 64 + 4 * c4] = h;
    }
    #pragma unroll
    for (int mi = 0; mi < 2; ++mi)
        #pragma unroll
        for (int nj = 0; nj < 4; ++nj)
            #pragma unroll
            for (int q = 0; q < 4; ++q) {
                const int row = w * 32 + mi * 16 + lk * 4 + q;
                const int col = nj * 16 + lr;
                E[row * LDE + col] = (__bf16)(c2 * acc[mi][nj][q]);
            }
    __syncthreads();

    f32x4 oacc[2][4] = {};
    #pragma unroll
    for (int ks = 0; ks < 4; ++ks) {
        bf16x8 a0 = *(const bf16x8*)&E[(w * 32 +  0 + lr) * LDE + ks * 32 + lk * 8];
        bf16x8 a1 = *(const bf16x8*)&E[(w * 32 + 16 + lr) * LDE + ks * 32 + lk * 8];
        #pragma unroll
        for (int nj = 0; nj < 4; ++nj) {
            bf16x8 bw = *(const bf16x8*)&Wt[(nj * 16 + lr) * LDE + ks * 32 + lk * 8];
            oacc[0][nj] = __builtin_amdgcn_mfma_f32_16x16x32_bf16(a0, bw, oacc[0][nj], 0, 0, 0);
            oacc[1][nj] = __builtin_amdgcn_mfma_f32_16x16x32_bf16(a1, bw, oacc[1][nj], 0, 0, 0);
        }
    }
    float* obt = out + (size_t)bt * N_ * C_;
    #pragma unroll
    for (int nj = 0; nj < 4; ++nj) {
        const float bv = bias[nj * 16 + lr];
        #pragma unroll
        for (int mi = 0; mi < 2; ++mi)
            #pragma unroll
            for (int q = 0; q < 4; ++q) {
                const int row = w * 32 + mi * 16 + lk * 4 + q;
                obt[(size_t)(m0 + row) * C_ + nj * 16 + lr] = oacc[mi][nj][q] + bv;
            }
    }
}

extern "C" void kernel_launch(void* const* d_in, const int* in_sizes, int n_in,
                              void* d_out, int out_size, void* d_ws, size_t ws_size,
                              hipStream_t stream) {
    const float* x       = (const float*)d_in[0];
    const float* adj     = (const float*)d_in[1];
    const float* st_emb  = (const float*)d_in[2];
    const float* weights = (const float*)d_in[3];
    const float* bias    = (const float*)d_in[4];
    const float* W1      = (const float*)d_in[5];
    const float* b1      = (const float*)d_in[6];
    const float* W2      = (const float*)d_in[7];
    const float* b2      = (const float*)d_in[8];
    float* out = (float*)d_out;
    char* ws = (char*)d_ws;
    float* cbuf = (float*)(ws + WS_CBUF);

    if (ws_size >= WS_NEED) {
        __bf16* WtB  = (__bf16*)(ws + WS_WTB);
        __bf16* adjb = (__bf16*)(ws + WS_ADJB);
        __bf16* xT   = (__bf16*)(ws + WS_XT);
        lamw_kernel<<<1, 512, 0, stream>>>(st_emb, W1, b1, W2, b2, weights, cbuf, WtB);
        cvt_fused<<<5120, 256, 0, stream>>>(x, xT, adj, adjb);
        dgcn_main2<<<dim3(N_ / BM, B_ * T_ / 2), 256, 0, stream>>>(adjb, xT, x, WtB, bias, cbuf, out);
    } else {
        lam_kernel<<<1, 384, 0, stream>>>(st_emb, W1, b1, W2, b2, cbuf);
        dgcn_fb<<<dim3(N_ / BM, B_ * T_), 256, 0, stream>>>(x, adj, weights, bias, cbuf, out);
    }
}

// Round 5
// 95.584 us; speedup vs baseline: 1.0373x; 1.0373x over previous
//
#include <hip/hip_runtime.h>
#include <hip/hip_bf16.h>

#define B_ 8
#define T_ 12
#define N_ 2048
#define C_ 64
#define BM 128
#define BK 64

typedef __attribute__((ext_vector_type(4))) float f32x4;
typedef __attribute__((ext_vector_type(4))) __bf16 bf16x4;
typedef __attribute__((ext_vector_type(8))) __bf16 bf16x8;

#define GAS __attribute__((address_space(1)))
#define LAS __attribute__((address_space(3)))

static __device__ __forceinline__ void gld_lds16(const void* g, void* l) {
    __builtin_amdgcn_global_load_lds((const GAS void*)g, (LAS void*)l, 16, 0, 0);
}

// ws layout (bytes)
#define WS_CBUF 0
#define WS_WTB  1024                                   // 16 KB
#define WS_ADJB 32768                                  // 8 MB
#define WS_P1T  (32768 + 8388608)                      // 24 MB
#define WS_P0S  (WS_P1T + 25165824)                    // 24 MB (full tier only)
#define WS_MID  ((size_t)WS_P0S)                       // 33,587,200 (proven available)
#define WS_FULL ((size_t)WS_P0S + 25165824)            // 58,753,024

// ---------------- lambda MLP (fallback path) ----------------
__global__ void lam_kernel(const float* __restrict__ st, const float* __restrict__ W1,
                           const float* __restrict__ b1, const float* __restrict__ W2,
                           const float* __restrict__ b2, float* __restrict__ cbuf) {
    const int t = threadIdx.x >> 5;
    const int h = threadIdx.x & 31;
    if (t >= T_) return;
    float acc = b1[h];
    #pragma unroll 8
    for (int e = 0; e < 64; ++e) acc += st[t * 64 + e] * W1[e * 32 + h];
    float hv = fmaxf(acc, 0.f) * W2[h];
    #pragma unroll
    for (int off = 16; off; off >>= 1) hv += __shfl_down(hv, off, 32);
    if (h == 0) {
        float lam = 1.f + fmaxf(hv + b2[0], 0.f);
        cbuf[t]      = 2.f - 2.f / lam;
        cbuf[T_ + t] = 2.f / lam;
    }
}

// ---------------- lambda MLP + Wcat->bf16 ----------------
__global__ void lamw_kernel(const float* __restrict__ st, const float* __restrict__ W1,
                            const float* __restrict__ b1, const float* __restrict__ W2,
                            const float* __restrict__ b2, const float* __restrict__ weights,
                            float* __restrict__ cbuf, __bf16* __restrict__ WtB) {
    const int t = threadIdx.x >> 5;
    const int h = threadIdx.x & 31;
    if (t < T_) {
        float acc = b1[h];
        #pragma unroll 8
        for (int e = 0; e < 64; ++e) acc += st[t * 64 + e] * W1[e * 32 + h];
        float hv = fmaxf(acc, 0.f) * W2[h];
        #pragma unroll
        for (int off = 16; off; off >>= 1) hv += __shfl_down(hv, off, 32);
        if (h == 0) {
            float lam = 1.f + fmaxf(hv + b2[0], 0.f);
            cbuf[t]      = 2.f - 2.f / lam;
            cbuf[T_ + t] = 2.f / lam;
        }
    }
    // WtB[o][k]: k<64 -> weights[1][k][o] (adj support), k>=64 -> weights[0][k-64][o] (identity)
    for (int e = threadIdx.x; e < 64 * 128; e += 512) {
        int o = e >> 7, k = e & 127;
        float v = (k < 64) ? weights[4096 + k * 64 + o] : weights[(k - 64) * 64 + o];
        WtB[o * 128 + k] = (__bf16)v;
    }
}

// ---------------- P kernel: P1T = (x@W1)^T bf16 ; P0 = c1*(x@W0)+bias ; + adj cvt ----------------
// blocks [0,1536): P per (bt, 128-row tile) ; blocks [1536, 3584): adj fp32->bf16
template<bool FULLP>
__global__ __launch_bounds__(256, 4) void pcvt_kernel(
    const float* __restrict__ x, const float* __restrict__ adj,
    const __bf16* __restrict__ WtB, const float* __restrict__ cbuf,
    const float* __restrict__ bias, __bf16* __restrict__ adjb,
    __bf16* __restrict__ P1T, __bf16* __restrict__ P0S, float* __restrict__ out)
{
    const int bid = blockIdx.x;
    const int tid = threadIdx.x;
    if (bid >= 1536) {
        const size_t i = ((size_t)(bid - 1536) * 256 + tid) * 8;
        const float4 f0 = *(const float4*)&adj[i];
        const float4 f1 = *(const float4*)&adj[i + 4];
        bf16x8 h = { (__bf16)f0.x, (__bf16)f0.y, (__bf16)f0.z, (__bf16)f0.w,
                     (__bf16)f1.x, (__bf16)f1.y, (__bf16)f1.z, (__bf16)f1.w };
        *(bf16x8*)&adjb[i] = h;
        return;
    }
    __shared__ __align__(16) __bf16 T[64 * 128];   // transpose tile, o-rows of 256 B
    char* TB = (char*)T;
    const int bt = bid >> 4, n0 = (bid & 15) * 128;
    const int l = tid & 63, w = tid >> 6;
    const int lr = l & 15, lk = l >> 4;
    const float c1 = cbuf[bt % T_];

    f32x4 p1[2][4] = {}, p0[2][4] = {};
    #pragma unroll
    for (int ks = 0; ks < 2; ++ks) {
        bf16x8 a[2];
        #pragma unroll
        for (int mi = 0; mi < 2; ++mi) {
            const float* xs = x + ((size_t)bt * N_ + n0 + w * 32 + mi * 16 + lr) * C_ + ks * 32 + lk * 8;
            float4 f0 = *(const float4*)xs;
            float4 f1 = *(const float4*)(xs + 4);
            a[mi] = { (__bf16)f0.x, (__bf16)f0.y, (__bf16)f0.z, (__bf16)f0.w,
                      (__bf16)f1.x, (__bf16)f1.y, (__bf16)f1.z, (__bf16)f1.w };
        }
        #pragma unroll
        for (int nj = 0; nj < 4; ++nj) {
            const __bf16* wb = WtB + (nj * 16 + lr) * 128 + ks * 32 + lk * 8;
            bf16x8 b1v = *(const bf16x8*)wb;
            bf16x8 b0v = *(const bf16x8*)(wb + 64);
            #pragma unroll
            for (int mi = 0; mi < 2; ++mi) {
                p1[mi][nj] = __builtin_amdgcn_mfma_f32_16x16x32_bf16(a[mi], b1v, p1[mi][nj], 0, 0, 0);
                p0[mi][nj] = __builtin_amdgcn_mfma_f32_16x16x32_bf16(a[mi], b0v, p0[mi][nj], 0, 0, 0);
            }
        }
    }
    // P0 term: c1*(x@W0) + bias -> out (f32) or P0S (bf16)
    #pragma unroll
    for (int nj = 0; nj < 4; ++nj) {
        const int o = nj * 16 + lr;
        const float bv = bias[o];
        #pragma unroll
        for (int mi = 0; mi < 2; ++mi)
            #pragma unroll
            for (int q = 0; q < 4; ++q) {
                const int row = w * 32 + mi * 16 + lk * 4 + q;
                const size_t idx = ((size_t)bt * N_ + n0 + row) * C_ + o;
                const float v = c1 * p0[mi][nj][q] + bv;
                if (FULLP) P0S[idx] = (__bf16)v; else out[idx] = v;
            }
    }
    // P1 -> LDS (swizzled) -> coalesced transposed write-out
    #pragma unroll
    for (int nj = 0; nj < 4; ++nj) {
        const int o = nj * 16 + lr;
        #pragma unroll
        for (int mi = 0; mi < 2; ++mi)
            #pragma unroll
            for (int q = 0; q < 4; ++q) {
                const int row = w * 32 + mi * 16 + lk * 4 + q;
                *(__bf16*)(TB + o * 256 + ((row * 2) ^ ((o & 7) << 4))) = (__bf16)p1[mi][nj][q];
            }
    }
    __syncthreads();
    {
        const int o = tid >> 2, seg = tid & 3;
        __bf16* dst = P1T + ((size_t)bt * 64 + o) * N_ + n0 + seg * 32;
        #pragma unroll
        for (int i = 0; i < 4; ++i) {
            const int chunk = seg * 64 + i * 16;
            *(bf16x8*)(dst + i * 8) = *(const bf16x8*)(TB + o * 256 + (chunk ^ ((o & 7) << 4)));
        }
    }
}

// ---------------- main kernel: out = c2*(adj @ P1) + P0term ----------------
// 128x192 block tile (3 bt), BK=64, double-buffered 2x40KB LDS, grid 16x32 = 512 = 2/CU exact.
template<bool FULLP>
__global__ __launch_bounds__(256, 2) void dgcn_main3(
    const __bf16* __restrict__ adjb, const __bf16* __restrict__ P1T,
    const __bf16* __restrict__ P0S, const float* __restrict__ cbuf,
    float* __restrict__ out)
{
    __shared__ __align__(16) __bf16 smem[40960];   // 81920 B
    char* sb = (char*)smem;

    const int m0  = blockIdx.x * BM;
    const int btg = blockIdx.y;                    // 0..31 (3 bt each)
    const int tid = threadIdx.x;
    const int l   = tid & 63, w = tid >> 6;
    const int wr  = w >> 1, wc = w & 1;
    const int lr  = l & 15, lk = l >> 4;

    // per-lane inverse-swizzled sources for global_load_lds (linear LDS dest)
    const __bf16* srcA[4];
    const __bf16* srcB[6];
    #pragma unroll
    for (int i = 0; i < 4; ++i) {
        int s = (w * 4 + i) * 64 + l;              // 0..1023  (A: 128 rows x 128B)
        int r = s >> 3, j = s & 7;
        srcA[i] = adjb + (size_t)(m0 + r) * N_ + 8 * (j ^ (r & 7));
    }
    #pragma unroll
    for (int i = 0; i < 6; ++i) {
        int s = (w * 6 + i) * 64 + l;              // 0..1535  (B: 3bt x 64 o-rows x 128B)
        int btl = s >> 9, rem = s & 511;
        int o = rem >> 3, j = rem & 7;
        srcB[i] = P1T + ((size_t)(btg * 3 + btl) * 64 + o) * N_ + 8 * (j ^ (o & 7));
    }

    f32x4 acc[4][6] = {};

    // prologue: stage kt=0 into buf0
    #pragma unroll
    for (int i = 0; i < 4; ++i) gld_lds16(srcA[i], sb + (w * 4 + i) * 1024);
    #pragma unroll
    for (int i = 0; i < 6; ++i) gld_lds16(srcB[i], sb + 16384 + (w * 6 + i) * 1024);

    int sel = 0;
    for (int kt = 0; kt < N_ / BK; ++kt) {
        __syncthreads();   // drains vmcnt(0): buf[sel] ready; prior reads of buf[sel^1] done
        if (kt < N_ / BK - 1) {
            const int wo = (sel ^ 1) * 40960;
            #pragma unroll
            for (int i = 0; i < 4; ++i) {
                srcA[i] += BK;
                gld_lds16(srcA[i], sb + wo + (w * 4 + i) * 1024);
            }
            #pragma unroll
            for (int i = 0; i < 6; ++i) {
                srcB[i] += BK;
                gld_lds16(srcB[i], sb + wo + 16384 + (w * 6 + i) * 1024);
            }
        }
        const char* base = sb + sel * 40960;
        #pragma unroll
        for (int ks = 0; ks < 2; ++ks) {
            const int kb = ks * 64 + lk * 16;
            bf16x8 a[4];
            #pragma unroll
            for (int mi = 0; mi < 4; ++mi) {
                int rr = wr * 64 + mi * 16 + lr;
                a[mi] = *(const bf16x8*)(base + rr * 128 + (kb ^ ((rr & 7) << 4)));
            }
            #pragma unroll
            for (int nj = 0; nj < 6; ++nj) {
                int c = wc * 96 + nj * 16 + lr;
                int btl = c >> 6, o = c & 63;
                bf16x8 b = *(const bf16x8*)(base + 16384 + btl * 8192 + o * 128 + (kb ^ ((o & 7) << 4)));
                #pragma unroll
                for (int mi = 0; mi < 4; ++mi)
                    acc[mi][nj] = __builtin_amdgcn_mfma_f32_16x16x32_bf16(a[mi], b, acc[mi][nj], 0, 0, 0);
            }
        }
        sel ^= 1;
    }

    // epilogue: out = c2*acc + P0term  (no LDS, no second GEMM)
    #pragma unroll
    for (int nj = 0; nj < 6; ++nj) {
        const int c = wc * 96 + nj * 16 + lr;
        const int btl = c >> 6, o = c & 63;
        const int btA = btg * 3 + btl;
        const float c2 = cbuf[T_ + (btA % T_)];
        #pragma unroll
        for (int mi = 0; mi < 4; ++mi)
            #pragma unroll
            for (int q = 0; q < 4; ++q) {
                const int row = wr * 64 + mi * 16 + lk * 4 + q;
                const size_t idx = ((size_t)btA * N_ + m0 + row) * C_ + o;
                const float p0v = FULLP ? (float)P0S[idx] : out[idx];
                out[idx] = c2 * acc[mi][nj][q] + p0v;
            }
    }
}

// ---------------- fallback (round-1 verified) ----------------
#define LDM 72
#define LDE 136
__global__ __launch_bounds__(256, 3) void dgcn_fb(
    const float* __restrict__ x, const float* __restrict__ adj,
    const float* __restrict__ weights, const float* __restrict__ bias,
    const float* __restrict__ cbuf, float* __restrict__ out)
{
    __shared__ __align__(16) __bf16 smem[BM * LDE];
    __shared__ __align__(16) __bf16 Wt[64 * LDE];
    __bf16* As = smem;
    __bf16* Bs = smem + BM * LDM;
    __bf16* E  = smem;

    const int mtile = blockIdx.x;
    const int bt    = blockIdx.y;
    const int tloc  = bt % T_;
    const int m0    = mtile * BM;
    const int tid   = threadIdx.x;
    const int lane  = tid & 63;
    const int w     = tid >> 6;

    const float c1 = cbuf[tloc];
    const float c2 = cbuf[T_ + tloc];
    const float* xbt = x + (size_t)bt * N_ * C_;

    for (int e = tid; e < 2 * 64 * 64; e += 256) {
        int kk = e >> 6, o = e & 63;
        float v = (kk < 64) ? weights[4096 + kk * 64 + o] : weights[(kk - 64) * 64 + o];
        Wt[o * LDE + kk] = (__bf16)v;
    }

    f32x4 acc[2][4] = {};
    const int c4 = tid & 15;
    const int rg = tid >> 4;
    const int lr = lane & 15;
    const int lk = lane >> 4;

    for (int kt = 0; kt < N_ / BK; ++kt) {
        const int k0 = kt * BK;
        __syncthreads();
        #pragma unroll
        for (int j = 0; j < 8; ++j) {
            const int r = rg + 16 * j;
            const float4 f = *(const float4*)&adj[(size_t)(m0 + r) * N_ + k0 + 4 * c4];
            bf16x4 h = { (__bf16)f.x, (__bf16)f.y, (__bf16)f.z, (__bf16)f.w };
            *(bf16x4*)&As[r * LDM + 4 * c4] = h;
        }
        #pragma unroll
        for (int j = 0; j < 4; ++j) {
            const int k  = (tid & 15) + 16 * j;
            const int c0 = 4 * (tid >> 4);
            const float4 f = *(const float4*)&xbt[(size_t)(k0 + k) * C_ + c0];
            Bs[(c0 + 0) * LDM + k] = (__bf16)f.x;
            Bs[(c0 + 1) * LDM + k] = (__bf16)f.y;
            Bs[(c0 + 2) * LDM + k] = (__bf16)f.z;
            Bs[(c0 + 3) * LDM + k] = (__bf16)f.w;
        }
        __syncthreads();
        #pragma unroll
        for (int ks = 0; ks < 2; ++ks) {
            bf16x8 a0 = *(const bf16x8*)&As[(w * 32 +  0 + lr) * LDM + ks * 32 + lk * 8];
            bf16x8 a1 = *(const bf16x8*)&As[(w * 32 + 16 + lr) * LDM + ks * 32 + lk * 8];
            #pragma unroll
            for (int nj = 0; nj < 4; ++nj) {
                bf16x8 b = *(const bf16x8*)&Bs[(nj * 16 + lr) * LDM + ks * 32 + lk * 8];
                acc[0][nj] = __builtin_amdgcn_mfma_f32_16x16x32_bf16(a0, b, acc[0][nj], 0, 0, 0);
                acc[1][nj] = __builtin_amdgcn_mfma_f32_16x16x32_bf16(a1, b, acc[1][nj], 0, 0, 0);
            }
        }
    }
    __syncthreads();

    #pragma unroll
    for (int j = 0; j < 8; ++j) {
        const int r = rg + 16 * j;
        const float4 f = *(const float4*)&xbt[(size_t)(m0 + r) * C_ + 4 * c4];
        bf16x4 h = { (__bf16)(c1 * f.x), (__bf16)(c1 * f.y), (__bf16)(c1 * f.z), (__bf16)(c1 * f.w) };
        *(bf16x4*)&E[r * LDE + 64 + 4 * c4] = h;
    }
    #pragma unroll
    for (int mi = 0; mi < 2; ++mi)
        #pragma unroll
        for (int nj = 0; nj < 4; ++nj)
            #pragma unroll
            for (int q = 0; q < 4; ++q) {
                const int row = w * 32 + mi * 16 + lk * 4 + q;
                const int col = nj * 16 + lr;
                E[row * LDE + col] = (__bf16)(c2 * acc[mi][nj][q]);
            }
    __syncthreads();

    f32x4 oacc[2][4] = {};
    #pragma unroll
    for (int ks = 0; ks < 4; ++ks) {
        bf16x8 a0 = *(const bf16x8*)&E[(w * 32 +  0 + lr) * LDE + ks * 32 + lk * 8];
        bf16x8 a1 = *(const bf16x8*)&E[(w * 32 + 16 + lr) * LDE + ks * 32 + lk * 8];
        #pragma unroll
        for (int nj = 0; nj < 4; ++nj) {
            bf16x8 bw = *(const bf16x8*)&Wt[(nj * 16 + lr) * LDE + ks * 32 + lk * 8];
            oacc[0][nj] = __builtin_amdgcn_mfma_f32_16x16x32_bf16(a0, bw, oacc[0][nj], 0, 0, 0);
            oacc[1][nj] = __builtin_amdgcn_mfma_f32_16x16x32_bf16(a1, bw, oacc[1][nj], 0, 0, 0);
        }
    }
    float* obt = out + (size_t)bt * N_ * C_;
    #pragma unroll
    for (int nj = 0; nj < 4; ++nj) {
        const float bv = bias[nj * 16 + lr];
        #pragma unroll
        for (int mi = 0; mi < 2; ++mi)
            #pragma unroll
            for (int q = 0; q < 4; ++q) {
                const int row = w * 32 + mi * 16 + lk * 4 + q;
                obt[(size_t)(m0 + row) * C_ + nj * 16 + lr] = oacc[mi][nj][q] + bv;
            }
    }
}

extern "C" void kernel_launch(void* const* d_in, const int* in_sizes, int n_in,
                              void* d_out, int out_size, void* d_ws, size_t ws_size,
                              hipStream_t stream) {
    const float* x       = (const float*)d_in[0];
    const float* adj     = (const float*)d_in[1];
    const float* st_emb  = (const float*)d_in[2];
    const float* weights = (const float*)d_in[3];
    const float* bias    = (const float*)d_in[4];
    const float* W1      = (const float*)d_in[5];
    const float* b1      = (const float*)d_in[6];
    const float* W2      = (const float*)d_in[7];
    const float* b2      = (const float*)d_in[8];
    float* out = (float*)d_out;
    char* ws = (char*)d_ws;
    float* cbuf = (float*)(ws + WS_CBUF);

    if (ws_size >= WS_MID) {
        __bf16* WtB  = (__bf16*)(ws + WS_WTB);
        __bf16* adjb = (__bf16*)(ws + WS_ADJB);
        __bf16* P1T  = (__bf16*)(ws + WS_P1T);
        __bf16* P0S  = (__bf16*)(ws + WS_P0S);   // only valid in full tier
        lamw_kernel<<<1, 512, 0, stream>>>(st_emb, W1, b1, W2, b2, weights, cbuf, WtB);
        if (ws_size >= WS_FULL) {
            pcvt_kernel<true><<<3584, 256, 0, stream>>>(x, adj, WtB, cbuf, bias, adjb, P1T, P0S, out);
            dgcn_main3<true><<<dim3(N_ / BM, 32), 256, 0, stream>>>(adjb, P1T, P0S, cbuf, out);
        } else {
            pcvt_kernel<false><<<3584, 256, 0, stream>>>(x, adj, WtB, cbuf, bias, adjb, P1T, P0S, out);
            dgcn_main3<false><<<dim3(N_ / BM, 32), 256, 0, stream>>>(adjb, P1T, P0S, cbuf, out);
        }
    } else {
        lam_kernel<<<1, 384, 0, stream>>>(st_emb, W1, b1, W2, b2, cbuf);
        dgcn_fb<<<dim3(N_ / BM, B_ * T_), 256, 0, stream>>>(x, adj, weights, bias, cbuf, out);
    }
}

// Round 6
// 93.308 us; speedup vs baseline: 1.0626x; 1.0244x over previous
//
#include <hip/hip_runtime.h>
#include <hip/hip_bf16.h>

#define B_ 8
#define T_ 12
#define N_ 2048
#define C_ 64
#define BM 128
#define BK 64

typedef __attribute__((ext_vector_type(4))) float f32x4;
typedef __attribute__((ext_vector_type(4))) __bf16 bf16x4;
typedef __attribute__((ext_vector_type(8))) __bf16 bf16x8;

#define GAS __attribute__((address_space(1)))
#define LAS __attribute__((address_space(3)))

static __device__ __forceinline__ void gld_lds16(const void* g, void* l) {
    __builtin_amdgcn_global_load_lds((const GAS void*)g, (LAS void*)l, 16, 0, 0);
}

// ws layout (bytes)
#define WS_CBUF 0
#define WS_WTB  1024                                   // 16 KB
#define WS_ADJB 32768                                  // 8 MB
#define WS_P1T  (32768 + 8388608)                      // 24 MB
#define WS_P0S  (WS_P1T + 25165824)                    // 24 MB (full tier only)
#define WS_MID  ((size_t)WS_P0S)                       // 33,587,200 (proven available)
#define WS_FULL ((size_t)WS_P0S + 25165824)            // 58,753,024

// ---------------- lambda MLP (fallback path) ----------------
__global__ void lam_kernel(const float* __restrict__ st, const float* __restrict__ W1,
                           const float* __restrict__ b1, const float* __restrict__ W2,
                           const float* __restrict__ b2, float* __restrict__ cbuf) {
    const int t = threadIdx.x >> 5;
    const int h = threadIdx.x & 31;
    if (t >= T_) return;
    float acc = b1[h];
    #pragma unroll 8
    for (int e = 0; e < 64; ++e) acc += st[t * 64 + e] * W1[e * 32 + h];
    float hv = fmaxf(acc, 0.f) * W2[h];
    #pragma unroll
    for (int off = 16; off; off >>= 1) hv += __shfl_down(hv, off, 32);
    if (h == 0) {
        float lam = 1.f + fmaxf(hv + b2[0], 0.f);
        cbuf[t]      = 2.f - 2.f / lam;
        cbuf[T_ + t] = 2.f / lam;
    }
}

// ---------------- lambda MLP + Wcat->bf16 ----------------
__global__ void lamw_kernel(const float* __restrict__ st, const float* __restrict__ W1,
                            const float* __restrict__ b1, const float* __restrict__ W2,
                            const float* __restrict__ b2, const float* __restrict__ weights,
                            float* __restrict__ cbuf, __bf16* __restrict__ WtB) {
    const int t = threadIdx.x >> 5;
    const int h = threadIdx.x & 31;
    if (t < T_) {
        float acc = b1[h];
        #pragma unroll 8
        for (int e = 0; e < 64; ++e) acc += st[t * 64 + e] * W1[e * 32 + h];
        float hv = fmaxf(acc, 0.f) * W2[h];
        #pragma unroll
        for (int off = 16; off; off >>= 1) hv += __shfl_down(hv, off, 32);
        if (h == 0) {
            float lam = 1.f + fmaxf(hv + b2[0], 0.f);
            cbuf[t]      = 2.f - 2.f / lam;
            cbuf[T_ + t] = 2.f / lam;
        }
    }
    // WtB[o][k]: k<64 -> weights[1][k][o] (adj support), k>=64 -> weights[0][k-64][o] (identity)
    for (int e = threadIdx.x; e < 64 * 128; e += 512) {
        int o = e >> 7, k = e & 127;
        float v = (k < 64) ? weights[4096 + k * 64 + o] : weights[(k - 64) * 64 + o];
        WtB[o * 128 + k] = (__bf16)v;
    }
}

// ---------------- P kernel: P1T = (x@W1)^T bf16 ; P0 = c1*(x@W0)+bias ; + adj cvt ----------------
// blocks [0,1536): P per (bt, 128-row tile) ; blocks [1536, 3584): adj fp32->bf16
template<bool FULLP>
__global__ __launch_bounds__(256, 4) void pcvt_kernel(
    const float* __restrict__ x, const float* __restrict__ adj,
    const __bf16* __restrict__ WtB, const float* __restrict__ cbuf,
    const float* __restrict__ bias, __bf16* __restrict__ adjb,
    __bf16* __restrict__ P1T, __bf16* __restrict__ P0S, float* __restrict__ out)
{
    const int bid = blockIdx.x;
    const int tid = threadIdx.x;
    if (bid >= 1536) {
        const size_t i = ((size_t)(bid - 1536) * 256 + tid) * 8;
        const float4 f0 = *(const float4*)&adj[i];
        const float4 f1 = *(const float4*)&adj[i + 4];
        bf16x8 h = { (__bf16)f0.x, (__bf16)f0.y, (__bf16)f0.z, (__bf16)f0.w,
                     (__bf16)f1.x, (__bf16)f1.y, (__bf16)f1.z, (__bf16)f1.w };
        *(bf16x8*)&adjb[i] = h;
        return;
    }
    __shared__ __align__(16) __bf16 T[64 * 128];   // transpose tile, o-rows of 256 B
    char* TB = (char*)T;
    const int bt = bid >> 4, n0 = (bid & 15) * 128;
    const int l = tid & 63, w = tid >> 6;
    const int lr = l & 15, lk = l >> 4;
    const float c1 = cbuf[bt % T_];

    f32x4 p1[2][4] = {}, p0[2][4] = {};
    #pragma unroll
    for (int ks = 0; ks < 2; ++ks) {
        bf16x8 a[2];
        #pragma unroll
        for (int mi = 0; mi < 2; ++mi) {
            const float* xs = x + ((size_t)bt * N_ + n0 + w * 32 + mi * 16 + lr) * C_ + ks * 32 + lk * 8;
            float4 f0 = *(const float4*)xs;
            float4 f1 = *(const float4*)(xs + 4);
            a[mi] = { (__bf16)f0.x, (__bf16)f0.y, (__bf16)f0.z, (__bf16)f0.w,
                      (__bf16)f1.x, (__bf16)f1.y, (__bf16)f1.z, (__bf16)f1.w };
        }
        #pragma unroll
        for (int nj = 0; nj < 4; ++nj) {
            const __bf16* wb = WtB + (nj * 16 + lr) * 128 + ks * 32 + lk * 8;
            bf16x8 b1v = *(const bf16x8*)wb;
            bf16x8 b0v = *(const bf16x8*)(wb + 64);
            #pragma unroll
            for (int mi = 0; mi < 2; ++mi) {
                p1[mi][nj] = __builtin_amdgcn_mfma_f32_16x16x32_bf16(a[mi], b1v, p1[mi][nj], 0, 0, 0);
                p0[mi][nj] = __builtin_amdgcn_mfma_f32_16x16x32_bf16(a[mi], b0v, p0[mi][nj], 0, 0, 0);
            }
        }
    }
    // P0 term: c1*(x@W0) + bias -> out (f32) or P0S (bf16)
    #pragma unroll
    for (int nj = 0; nj < 4; ++nj) {
        const int o = nj * 16 + lr;
        const float bv = bias[o];
        #pragma unroll
        for (int mi = 0; mi < 2; ++mi)
            #pragma unroll
            for (int q = 0; q < 4; ++q) {
                const int row = w * 32 + mi * 16 + lk * 4 + q;
                const size_t idx = ((size_t)bt * N_ + n0 + row) * C_ + o;
                const float v = c1 * p0[mi][nj][q] + bv;
                if (FULLP) P0S[idx] = (__bf16)v; else out[idx] = v;
            }
    }
    // P1 -> LDS (swizzled) -> coalesced transposed write-out
    #pragma unroll
    for (int nj = 0; nj < 4; ++nj) {
        const int o = nj * 16 + lr;
        #pragma unroll
        for (int mi = 0; mi < 2; ++mi)
            #pragma unroll
            for (int q = 0; q < 4; ++q) {
                const int row = w * 32 + mi * 16 + lk * 4 + q;
                *(__bf16*)(TB + o * 256 + ((row * 2) ^ ((o & 7) << 4))) = (__bf16)p1[mi][nj][q];
            }
    }
    __syncthreads();
    {
        const int o = tid >> 2, seg = tid & 3;
        __bf16* dst = P1T + ((size_t)bt * 64 + o) * N_ + n0 + seg * 32;
        #pragma unroll
        for (int i = 0; i < 4; ++i) {
            const int chunk = seg * 64 + i * 16;
            *(bf16x8*)(dst + i * 8) = *(const bf16x8*)(TB + o * 256 + (chunk ^ ((o & 7) << 4)));
        }
    }
}

// ---------------- main kernel: out = c2*(adj @ P1) + P0term ----------------
// 128x192 block tile (3 bt), BK=64, 2x40KB LDS dbuf, prefetch depth 2,
// counted s_waitcnt vmcnt(10) (T4) — loads stay in flight across barriers.
template<bool FULLP>
__global__ __launch_bounds__(256, 2) void dgcn_main4(
    const __bf16* __restrict__ adjb, const __bf16* __restrict__ P1T,
    const __bf16* __restrict__ P0S, const float* __restrict__ cbuf,
    float* __restrict__ out)
{
    __shared__ __align__(16) __bf16 smem[40960];   // 81920 B
    char* sb = (char*)smem;

    const int m0  = blockIdx.x * BM;
    const int btg = blockIdx.y;                    // 0..31 (3 bt each)
    const int tid = threadIdx.x;
    const int l   = tid & 63, w = tid >> 6;
    const int wr  = w >> 1, wc = w & 1;
    const int lr  = l & 15, lk = l >> 4;

    // per-lane inverse-swizzled sources for global_load_lds (linear LDS dest)
    const __bf16* srcA[4];
    const __bf16* srcB[6];
    #pragma unroll
    for (int i = 0; i < 4; ++i) {
        int s = (w * 4 + i) * 64 + l;              // 0..1023  (A: 128 rows x 128B)
        int r = s >> 3, j = s & 7;
        srcA[i] = adjb + (size_t)(m0 + r) * N_ + 8 * (j ^ (r & 7));
    }
    #pragma unroll
    for (int i = 0; i < 6; ++i) {
        int s = (w * 6 + i) * 64 + l;              // 0..1535  (B: 3bt x 64 o-rows x 128B)
        int btl = s >> 9, rem = s & 511;
        int o = rem >> 3, j = rem & 7;
        srcB[i] = P1T + ((size_t)(btg * 3 + btl) * 64 + o) * N_ + 8 * (j ^ (o & 7));
    }

    f32x4 acc[4][6] = {};

    // stage tile (10 loads/thread) into buffer `bufsel`, then advance pointers by BK
    auto STAGE = [&]__attribute__((always_inline))(int bufsel) {
        const int wo = bufsel * 40960;
        #pragma unroll
        for (int i = 0; i < 4; ++i) {
            gld_lds16(srcA[i], sb + wo + (w * 4 + i) * 1024);
            srcA[i] += BK;
        }
        #pragma unroll
        for (int i = 0; i < 6; ++i) {
            gld_lds16(srcB[i], sb + wo + 16384 + (w * 6 + i) * 1024);
            srcB[i] += BK;
        }
    };

    // prologue: prefetch depth 2 (20 loads in flight)
    STAGE(0);
    STAGE(1);

    const int NT = N_ / BK;                        // 32
    int sel = 0;
    for (int kt = 0; kt < NT; ++kt) {
        // wait only the OLDEST tile's 10 loads (counted vmcnt, T4); drain fully on last iter
        if (kt == NT - 1) asm volatile("s_waitcnt vmcnt(0)" ::: "memory");
        else              asm volatile("s_waitcnt vmcnt(10)" ::: "memory");
        __builtin_amdgcn_sched_barrier(0);
        __builtin_amdgcn_s_barrier();              // buf[sel] ready for ALL waves

        const char* base = sb + sel * 40960;
        #pragma unroll
        for (int ks = 0; ks < 2; ++ks) {
            const int kb = ks * 64 + lk * 16;
            bf16x8 a[4];
            #pragma unroll
            for (int mi = 0; mi < 4; ++mi) {
                int rr = wr * 64 + mi * 16 + lr;
                a[mi] = *(const bf16x8*)(base + rr * 128 + (kb ^ ((rr & 7) << 4)));
            }
            #pragma unroll
            for (int nj = 0; nj < 6; ++nj) {
                int c = wc * 96 + nj * 16 + lr;
                int btl = c >> 6, o = c & 63;
                bf16x8 b = *(const bf16x8*)(base + 16384 + btl * 8192 + o * 128 + (kb ^ ((o & 7) << 4)));
                #pragma unroll
                for (int mi = 0; mi < 4; ++mi)
                    acc[mi][nj] = __builtin_amdgcn_mfma_f32_16x16x32_bf16(a[mi], b, acc[mi][nj], 0, 0, 0);
            }
        }

        __builtin_amdgcn_s_barrier();              // all waves done READING buf[sel]
        if (kt + 2 < NT) STAGE(sel);               // re-stage consumed buffer for kt+2
        sel ^= 1;
    }

    // epilogue: out = c2*acc + P0term  (no LDS)
    #pragma unroll
    for (int nj = 0; nj < 6; ++nj) {
        const int c = wc * 96 + nj * 16 + lr;
        const int btl = c >> 6, o = c & 63;
        const int btA = btg * 3 + btl;
        const float c2 = cbuf[T_ + (btA % T_)];
        #pragma unroll
        for (int mi = 0; mi < 4; ++mi)
            #pragma unroll
            for (int q = 0; q < 4; ++q) {
                const int row = wr * 64 + mi * 16 + lk * 4 + q;
                const size_t idx = ((size_t)btA * N_ + m0 + row) * C_ + o;
                const float p0v = FULLP ? (float)P0S[idx] : out[idx];
                out[idx] = c2 * acc[mi][nj][q] + p0v;
            }
    }
}

// ---------------- fallback (round-1 verified) ----------------
#define LDM 72
#define LDE 136
__global__ __launch_bounds__(256, 3) void dgcn_fb(
    const float* __restrict__ x, const float* __restrict__ adj,
    const float* __restrict__ weights, const float* __restrict__ bias,
    const float* __restrict__ cbuf, float* __restrict__ out)
{
    __shared__ __align__(16) __bf16 smem[BM * LDE];
    __shared__ __align__(16) __bf16 Wt[64 * LDE];
    __bf16* As = smem;
    __bf16* Bs = smem + BM * LDM;
    __bf16* E  = smem;

    const int mtile = blockIdx.x;
    const int bt    = blockIdx.y;
    const int tloc  = bt % T_;
    const int m0    = mtile * BM;
    const int tid   = threadIdx.x;
    const int lane  = tid & 63;
    const int w     = tid >> 6;

    const float c1 = cbuf[tloc];
    const float c2 = cbuf[T_ + tloc];
    const float* xbt = x + (size_t)bt * N_ * C_;

    for (int e = tid; e < 2 * 64 * 64; e += 256) {
        int kk = e >> 6, o = e & 63;
        float v = (kk < 64) ? weights[4096 + kk * 64 + o] : weights[(kk - 64) * 64 + o];
        Wt[o * LDE + kk] = (__bf16)v;
    }

    f32x4 acc[2][4] = {};
    const int c4 = tid & 15;
    const int rg = tid >> 4;
    const int lr = lane & 15;
    const int lk = lane >> 4;

    for (int kt = 0; kt < N_ / BK; ++kt) {
        const int k0 = kt * BK;
        __syncthreads();
        #pragma unroll
        for (int j = 0; j < 8; ++j) {
            const int r = rg + 16 * j;
            const float4 f = *(const float4*)&adj[(size_t)(m0 + r) * N_ + k0 + 4 * c4];
            bf16x4 h = { (__bf16)f.x, (__bf16)f.y, (__bf16)f.z, (__bf16)f.w };
            *(bf16x4*)&As[r * LDM + 4 * c4] = h;
        }
        #pragma unroll
        for (int j = 0; j < 4; ++j) {
            const int k  = (tid & 15) + 16 * j;
            const int c0 = 4 * (tid >> 4);
            const float4 f = *(const float4*)&xbt[(size_t)(k0 + k) * C_ + c0];
            Bs[(c0 + 0) * LDM + k] = (__bf16)f.x;
            Bs[(c0 + 1) * LDM + k] = (__bf16)f.y;
            Bs[(c0 + 2) * LDM + k] = (__bf16)f.z;
            Bs[(c0 + 3) * LDM + k] = (__bf16)f.w;
        }
        __syncthreads();
        #pragma unroll
        for (int ks = 0; ks < 2; ++ks) {
            bf16x8 a0 = *(const bf16x8*)&As[(w * 32 +  0 + lr) * LDM + ks * 32 + lk * 8];
            bf16x8 a1 = *(const bf16x8*)&As[(w * 32 + 16 + lr) * LDM + ks * 32 + lk * 8];
            #pragma unroll
            for (int nj = 0; nj < 4; ++nj) {
                bf16x8 b = *(const bf16x8*)&Bs[(nj * 16 + lr) * LDM + ks * 32 + lk * 8];
                acc[0][nj] = __builtin_amdgcn_mfma_f32_16x16x32_bf16(a0, b, acc[0][nj], 0, 0, 0);
                acc[1][nj] = __builtin_amdgcn_mfma_f32_16x16x32_bf16(a1, b, acc[1][nj], 0, 0, 0);
            }
        }
    }
    __syncthreads();

    #pragma unroll
    for (int j = 0; j < 8; ++j) {
        const int r = rg + 16 * j;
        const float4 f = *(const float4*)&xbt[(size_t)(m0 + r) * C_ + 4 * c4];
        bf16x4 h = { (__bf16)(c1 * f.x), (__bf16)(c1 * f.y), (__bf16)(c1 * f.z), (__bf16)(c1 * f.w) };
        *(bf16x4*)&E[r * LDE + 64 + 4 * c4] = h;
    }
    #pragma unroll
    for (int mi = 0; mi < 2; ++mi)
        #pragma unroll
        for (int nj = 0; nj < 4; ++nj)
            #pragma unroll
            for (int q = 0; q < 4; ++q) {
                const int row = w * 32 + mi * 16 + lk * 4 + q;
                const int col = nj * 16 + lr;
                E[row * LDE + col] = (__bf16)(c2 * acc[mi][nj][q]);
            }
    __syncthreads();

    f32x4 oacc[2][4] = {};
    #pragma unroll
    for (int ks = 0; ks < 4; ++ks) {
        bf16x8 a0 = *(const bf16x8*)&E[(w * 32 +  0 + lr) * LDE + ks * 32 + lk * 8];
        bf16x8 a1 = *(const bf16x8*)&E[(w * 32 + 16 + lr) * LDE + ks * 32 + lk * 8];
        #pragma unroll
        for (int nj = 0; nj < 4; ++nj) {
            bf16x8 bw = *(const bf16x8*)&Wt[(nj * 16 + lr) * LDE + ks * 32 + lk * 8];
            oacc[0][nj] = __builtin_amdgcn_mfma_f32_16x16x32_bf16(a0, bw, oacc[0][nj], 0, 0, 0);
            oacc[1][nj] = __builtin_amdgcn_mfma_f32_16x16x32_bf16(a1, bw, oacc[1][nj], 0, 0, 0);
        }
    }
    float* obt = out + (size_t)bt * N_ * C_;
    #pragma unroll
    for (int nj = 0; nj < 4; ++nj) {
        const float bv = bias[nj * 16 + lr];
        #pragma unroll
        for (int mi = 0; mi < 2; ++mi)
            #pragma unroll
            for (int q = 0; q < 4; ++q) {
                const int row = w * 32 + mi * 16 + lk * 4 + q;
                obt[(size_t)(m0 + row) * C_ + nj * 16 + lr] = oacc[mi][nj][q] + bv;
            }
    }
}

extern "C" void kernel_launch(void* const* d_in, const int* in_sizes, int n_in,
                              void* d_out, int out_size, void* d_ws, size_t ws_size,
                              hipStream_t stream) {
    const float* x       = (const float*)d_in[0];
    const float* adj     = (const float*)d_in[1];
    const float* st_emb  = (const float*)d_in[2];
    const float* weights = (const float*)d_in[3];
    const float* bias    = (const float*)d_in[4];
    const float* W1      = (const float*)d_in[5];
    const float* b1      = (const float*)d_in[6];
    const float* W2      = (const float*)d_in[7];
    const float* b2      = (const float*)d_in[8];
    float* out = (float*)d_out;
    char* ws = (char*)d_ws;
    float* cbuf = (float*)(ws + WS_CBUF);

    if (ws_size >= WS_MID) {
        __bf16* WtB  = (__bf16*)(ws + WS_WTB);
        __bf16* adjb = (__bf16*)(ws + WS_ADJB);
        __bf16* P1T  = (__bf16*)(ws + WS_P1T);
        __bf16* P0S  = (__bf16*)(ws + WS_P0S);   // only valid in full tier
        lamw_kernel<<<1, 512, 0, stream>>>(st_emb, W1, b1, W2, b2, weights, cbuf, WtB);
        if (ws_size >= WS_FULL) {
            pcvt_kernel<true><<<3584, 256, 0, stream>>>(x, adj, WtB, cbuf, bias, adjb, P1T, P0S, out);
            dgcn_main4<true><<<dim3(N_ / BM, 32), 256, 0, stream>>>(adjb, P1T, P0S, cbuf, out);
        } else {
            pcvt_kernel<false><<<3584, 256, 0, stream>>>(x, adj, WtB, cbuf, bias, adjb, P1T, P0S, out);
            dgcn_main4<false><<<dim3(N_ / BM, 32), 256, 0, stream>>>(adjb, P1T, P0S, cbuf, out);
        }
    } else {
        lam_kernel<<<1, 384, 0, stream>>>(st_emb, W1, b1, W2, b2, cbuf);
        dgcn_fb<<<dim3(N_ / BM, B_ * T_), 256, 0, stream>>>(x, adj, weights, bias, cbuf, out);
    }
}